// Round 3
// baseline (3378.691 us; speedup 1.0000x reference)
//
#include <hip/hip_runtime.h>

typedef unsigned short u16;
typedef unsigned int   u32;
typedef unsigned long long u64;
typedef short s16x8 __attribute__((ext_vector_type(8)));
typedef float f32x4 __attribute__((ext_vector_type(4)));
typedef u32   u32x2 __attribute__((ext_vector_type(2)));
typedef _Float16 f16x8 __attribute__((ext_vector_type(8)));

#define S_LEN 2048
#define BATCH 64
#define H_DIM 300
#define HP    304   // padded N (output) dim for pooled
#define KP    320   // padded K (contraction) dim

// ws layout (bytes)
#define OFF_WPAD 0u         // 304*320*2 = 194,560
#define OFF_BIAS 196608u    // 304*4
#define OFF_FLAG 198656u    // 4
#define OFF_H    200704u    // 64*320*2 = 40,960 (f16 h state, [b][k])
#define OFF_POOL 278528u    // 2048*304*4 = 2,490,368
#define OFF_WHH  2768896u   // 320*320*2 = 204,800 (f16 W_hh, [n][k], zero-pad)
#define OFF_XP   3158016u   // CH*19*16*64*4 (f32, [s][nt][lm][b])

__device__ __forceinline__ float bf2f(u16 u){
  union { u32 i; float f; } v; v.i = ((u32)u) << 16; return v.f;
}
__device__ __forceinline__ u16 f2bf(float f){
  u32 i = __float_as_uint(f);
  u32 r = (i + 0x7fffu + ((i >> 16) & 1u)) >> 16;
  return (u16)r;
}
__device__ __forceinline__ u16 f2h(float f){
  union { _Float16 h; u16 u; } v; v.h = (_Float16)f; return v.u;
}
// packed f32x2 -> f16x2 (RTZ), returned as u32 (builtin returns __fp16x2)
__device__ __forceinline__ u32 pkh2(float a, float b){
  auto p = __builtin_amdgcn_cvt_pkrtz(a, b);
  union { decltype(p) h; u32 u; } v; v.h = p; return v.u;
}

template<int N>
__device__ __forceinline__ void wait_lgkm(){
  asm volatile("s_waitcnt lgkmcnt(%0)" :: "n"(N) : "memory");
}
#define SBAR0() __builtin_amdgcn_sched_barrier(0)

// LDS-only barrier: no vmcnt drain (atomics/xp prefetch stay in flight).
#define BAR_LDS() do {                                        \
    __builtin_amdgcn_sched_barrier(0);                        \
    asm volatile("s_waitcnt lgkmcnt(0)" ::: "memory");        \
    __builtin_amdgcn_s_barrier();                             \
    __builtin_amdgcn_sched_barrier(0);                        \
  } while (0)

// ---------------------------------------------------------------------------
// detect: f32 vs bf16 input storage (bf16 emb exponents < 135 always).
// ---------------------------------------------------------------------------
__global__ __launch_bounds__(256) void detect(const u16* __restrict__ emb_raw,
                                              int* __restrict__ flag){
  __shared__ int big;
  if (threadIdx.x == 0) big = 0;
  __syncthreads();
  int loc = 0;
  for (int i = threadIdx.x; i < 1024; i += 256){
    const u32 e = ((u32)emb_raw[i] >> 7) & 0xFFu;
    if (e >= 135u) loc = 1;
  }
  if (loc) atomicOr(&big, 1);
  __syncthreads();
  if (threadIdx.x == 0) *flag = big;   // 1 = f32 inputs, 0 = bf16 inputs
}

// ---------------------------------------------------------------------------
// prep: zero pooled / h state; padded bf16 W_ih [304][320]; fused fp32 bias;
// f16 W_hh [320 n][320 k] row-major, zero-padded (MFMA B-fragment source).
// ---------------------------------------------------------------------------
__global__ __launch_bounds__(256) void prep(
    const void* __restrict__ Wih_raw, const void* __restrict__ Whh_raw,
    const void* __restrict__ bih_raw, const void* __restrict__ bhh_raw,
    const int* __restrict__ flag,
    u16* __restrict__ Wpad, u16* __restrict__ Whhp,
    float* __restrict__ biasp, float* __restrict__ pooled,
    u32* __restrict__ hstate32)
{
  const bool isf32 = (*flag != 0);
  const int idx = blockIdx.x * 256 + threadIdx.x;
  if (idx < S_LEN * HP) pooled[idx] = 0.f;
  if (idx < BATCH * 160) hstate32[idx] = 0u;      // 40,960 B of f16 zeros
  if (idx < 320 * 320){
    const int r = idx / 320, k = idx % 320;       // r = n (output), k = input
    float w = 0.f;
    if (r < H_DIM && k < H_DIM){
      w = isf32 ? ((const float*)Whh_raw)[r * H_DIM + k]
                : bf2f(((const u16*)Whh_raw)[r * H_DIM + k]);
    }
    Whhp[idx] = f2h(w);
  }
  if (idx < HP * KP){
    const int n = idx / KP, k = idx % KP;
    u16 v = 0;
    if (n < H_DIM && k < H_DIM){
      v = isf32 ? f2bf(((const float*)Wih_raw)[n * H_DIM + k])
                : ((const u16*)Wih_raw)[n * H_DIM + k];
    }
    Wpad[idx] = v;
  }
  if (idx < HP){
    float bv = 0.f;
    if (idx < H_DIM){
      bv = isf32 ? (((const float*)bih_raw)[idx] + ((const float*)bhh_raw)[idx])
                 : (bf2f(((const u16*)bih_raw)[idx]) + bf2f(((const u16*)bhh_raw)[idx]));
    }
    biasp[idx] = bv;
  }
}

// ---------------------------------------------------------------------------
// xp_gemm: one block per timestep (64 batches), MFMA 16x16x32 bf16.
// Output layout [srel][nt(19)][lm(16)][b(64)] f32 so recur's consumer lane
// reads its 4 batches as ONE dwordx4 (b contiguous). Bias folded in.
// ---------------------------------------------------------------------------
__global__ __launch_bounds__(256) void xp_gemm(
    const int* __restrict__ x, const void* __restrict__ emb_raw,
    const int* __restrict__ flag,
    const u16* __restrict__ Wpad, const float* __restrict__ biasp,
    float* __restrict__ xp, int s0)
{
  __shared__ u16 A[64 * KP];                 // 40 KB
  const bool isf32 = (*flag != 0);
  const int tid = threadIdx.x;
  const int m0g = s0 * BATCH + blockIdx.x * 64;   // global m of row 0

  for (int t = tid; t < 640; t += 256){
    const int row = t / 10, wd = t % 10;
    *(u32*)&A[row * KP + H_DIM + wd * 2] = 0u;
  }
  for (int t = tid; t < 64 * 75; t += 256){
    const int row = t / 75, off = t % 75;
    const int tok = x[m0g + row];
    u64 pk;
    if (isf32){
      const float4 v = *(const float4*)((const float*)emb_raw + (size_t)tok * H_DIM + off * 4);
      pk = (u64)f2bf(v.x) | ((u64)f2bf(v.y) << 16)
         | ((u64)f2bf(v.z) << 32) | ((u64)f2bf(v.w) << 48);
    } else {
      pk = *(const u64*)((const u16*)emb_raw + (size_t)tok * H_DIM + off * 4);
    }
    *(u64*)&A[row * KP + off * 4] = pk;
  }
  __syncthreads();

  const int wave = tid >> 6, lane = tid & 63;
  const int lm = lane & 15, lq = lane >> 4;

  f32x4 acc[19];
#pragma unroll
  for (int nt = 0; nt < 19; ++nt) acc[nt] = (f32x4){0.f, 0.f, 0.f, 0.f};

#pragma unroll
  for (int ks = 0; ks < 10; ++ks){
    const int k = ks * 32 + lq * 8;
    const s16x8 af = *(const s16x8*)&A[(wave * 16 + lm) * KP + k];
#pragma unroll
    for (int nt = 0; nt < 19; ++nt){
      const s16x8 bf = *(const s16x8*)&Wpad[(nt * 16 + lm) * KP + k];
      acc[nt] = __builtin_amdgcn_mfma_f32_16x16x32_bf16(af, bf, acc[nt], 0, 0, 0);
    }
  }
#pragma unroll
  for (int nt = 0; nt < 19; ++nt){
    const int n = nt * 16 + lm;
    const float bv = biasp[n];
    f32x4 o = acc[nt];
    o[0] += bv; o[1] += bv; o[2] += bv; o[3] += bv;
    // [srel][nt][lm][b]: b = wave*16 + lq*4 + rr (rr contiguous -> vec4 store)
    *(f32x4*)&xp[((size_t)(blockIdx.x * 19 + nt) * 16 + lm) * 64 + wave * 16 + lq * 4] = o;
  }
}

// ---------------------------------------------------------------------------
// recur: 4 blocks x 16 batches, 256 threads = 4 waves (1/SIMD). Per step the
// block computes H_next(16x320) = relu(H(16x320) @ Whh^T + xp) with
// 200 MFMA f32_16x16x32_f16 (wave w owns n-tiles 5w..5w+4; tile 19 is pad).
// W_hh B-fragments resident in VGPRs (50 x f16x8 = 200 VGPR). h lives in LDS
// as f16 [k=320][b=16]; written from C-layout via cvt_pkrtz + ds_write_b64,
// read back as A-fragments via ds_read_b64_tr_b16 (HW transpose), pipelined
// 6 pairs deep under counted lgkmcnt. Barriers are lgkm-only; pooled
// atomicMax + dout stores are fire-and-forget.
// ---------------------------------------------------------------------------
__global__ __launch_bounds__(256, 1) void recur(
    const float* __restrict__ xp, const u16* __restrict__ Whhp,
    u16* __restrict__ hstate, float* __restrict__ pooled,
    float* __restrict__ dout, int s0, int len)
{
  const int bblk = blockIdx.x;
  const int tid  = threadIdx.x;
  const int w  = tid >> 6, l = tid & 63;
  const int lm = l & 15,  lq = l >> 4;
  const int tW = w * 5;                    // first n-tile of this wave

  __shared__ u16 hkb[320 * 16];            // h as f16, elem = k*16 + b (10 KB)

  // ---- B-fragment preload: bq[i][ks] = Whh[n = (tW+i)*16+lm][k = ks*32+lq*8 ..+8]
  f16x8 bq[5][10];
#pragma unroll
  for (int i = 0; i < 5; ++i){
    const u16* wr = Whhp + (size_t)((tW + i) * 16 + lm) * 320;
#pragma unroll
    for (int ks = 0; ks < 10; ++ks)
      bq[i][ks] = *(const f16x8*)(wr + ks * 32 + lq * 8);
  }

  // ---- h init: hstate [b][k] f16 -> hkb [k][b]
  for (int idx = tid; idx < 320 * 16; idx += 256){
    const int k = idx >> 4, b = idx & 15;
    hkb[idx] = hstate[(size_t)(bblk * 16 + b) * 320 + k];
  }

  // ---- xp base: element ((t*19 + nt)*16 + lm)*64 + bblk*16 + lq*4
  const float* xq = xp + (size_t)lm * 64 + bblk * 16 + lq * 4;
  f32x4 xv[5];
#pragma unroll
  for (int i = 0; i < 5; ++i){
    xv[i] = (f32x4){0.f, 0.f, 0.f, 0.f};
    if (tW + i < 19) xv[i] = *(const f32x4*)(xq + (size_t)(tW + i) * 1024);
  }
  __syncthreads();

  // tr-read per-lane base (bytes): group lq covers a [4k][16b] 128B tile.
  const int vaddr = lq * 256 + lm * 8;
  const bool lastChunk = (s0 + len == S_LEN);

  f32x4 acc[5];

  for (int t = 0; t < len; ++t){
    // ---- prefetch next step's xp (hides under MFMA phase)
    const int tn = (t + 1 < len) ? (t + 1) : t;
    f32x4 xn[5];
#pragma unroll
    for (int i = 0; i < 5; ++i){
      xn[i] = (f32x4){0.f, 0.f, 0.f, 0.f};
      if (tW + i < 19) xn[i] = *(const f32x4*)(xq + (size_t)(tn * 19 + tW + i) * 1024);
    }

    // ---- A-fragment tr reads, 6 pairs in flight, + MFMA per k-step
    u32x2 t0[10], t1[10];
#define ISSUE(KS)                                                         \
    asm volatile("ds_read_b64_tr_b16 %0, %2 offset:%3\n\t"                \
                 "ds_read_b64_tr_b16 %1, %2 offset:%4"                    \
                 : "=v"(t0[KS]), "=v"(t1[KS])                             \
                 : "v"(vaddr), "n"(KS * 1024), "n"(KS * 1024 + 128))

#define MF(KS, FIRST) {                                                   \
    asm volatile("" : "+v"(t0[KS]), "+v"(t1[KS]));                        \
    union { u32 uu[4]; f16x8 h; } afu;                                    \
    afu.uu[0] = t0[KS].x; afu.uu[1] = t0[KS].y;                           \
    afu.uu[2] = t1[KS].x; afu.uu[3] = t1[KS].y;                           \
    _Pragma("unroll")                                                     \
    for (int i = 0; i < 5; ++i)                                           \
      acc[i] = __builtin_amdgcn_mfma_f32_16x16x32_f16(                    \
          afu.h, bq[i][KS],                                               \
          (FIRST) ? (f32x4){0.f,0.f,0.f,0.f} : acc[i], 0, 0, 0);          \
  }

    ISSUE(0); ISSUE(1); ISSUE(2); ISSUE(3); ISSUE(4); ISSUE(5);
    ISSUE(6);  wait_lgkm<12>(); SBAR0(); MF(0, true);
    ISSUE(7);  wait_lgkm<12>(); SBAR0(); MF(1, false);
    ISSUE(8);  wait_lgkm<12>(); SBAR0(); MF(2, false);
    ISSUE(9);  wait_lgkm<12>(); SBAR0(); MF(3, false);
    wait_lgkm<10>(); SBAR0(); MF(4, false);
    wait_lgkm<8>();  SBAR0(); MF(5, false);
    wait_lgkm<6>();  SBAR0(); MF(6, false);
    wait_lgkm<4>();  SBAR0(); MF(7, false);
    wait_lgkm<2>();  SBAR0(); MF(8, false);
    wait_lgkm<0>();  SBAR0(); MF(9, false);
#undef ISSUE
#undef MF

    // all waves finished reading h for this step before anyone overwrites it
    __builtin_amdgcn_s_barrier();
    SBAR0();

    // ---- epilogue: h = relu(acc + xp); pack f16 -> hkb[k][b]; pooled max
    const int sAbs = s0 + t;
    const bool wrLast = lastChunk && (t == len - 1);
#pragma unroll
    for (int i = 0; i < 5; ++i){
      const int nB = (tW + i) * 16;
      f32x4 hv;
#pragma unroll
      for (int rr = 0; rr < 4; ++rr)
        hv[rr] = fmaxf(acc[i][rr] + xv[i][rr], 0.f);

      const u32 c0 = pkh2(hv[0], hv[1]);
      const u32 c1 = pkh2(hv[2], hv[3]);
      *(u32x2*)&hkb[(nB + lm) * 16 + lq * 4] = (u32x2){c0, c1};

      const int n = nB + lm;
      if (n < H_DIM){
        const float mx = fmaxf(fmaxf(hv[0], hv[1]), fmaxf(hv[2], hv[3]));
        atomicMax((u32*)(pooled + (size_t)sAbs * HP + n), __float_as_uint(mx));
        if (wrLast){
          const int bg = bblk * 16 + lq * 4;
#pragma unroll
          for (int rr = 0; rr < 4; ++rr)
            dout[S_LEN * 2 + (size_t)(bg + rr) * H_DIM + n] = hv[rr];
        }
      }
#pragma unroll
      for (int rr = 0; rr < 4; ++rr) xv[i][rr] = xn[i][rr];
    }
    BAR_LDS();    // h_next visible to all waves (no vmcnt drain)
  }

  // ---- writeback h state
  for (int idx = tid; idx < 320 * 16; idx += 256){
    const int k = idx >> 4, b = idx & 15;
    hstate[(size_t)(bblk * 16 + b) * 320 + k] = hkb[idx];
  }
}

// ---------------------------------------------------------------------------
// outproj: out[s][c] = sum_i pooled[s][i] * W_out[c][i] + b_out[c]  (f32 out)
// ---------------------------------------------------------------------------
__global__ __launch_bounds__(128) void outproj(
    const float* __restrict__ pooled, const void* __restrict__ Wout_raw,
    const void* __restrict__ bout_raw, const int* __restrict__ flag,
    float* __restrict__ dout)
{
  const bool isf32 = (*flag != 0);
  const int s = blockIdx.x * 128 + threadIdx.x;   // 0..2047
  float a0, a1;
  if (isf32){ a0 = ((const float*)bout_raw)[0]; a1 = ((const float*)bout_raw)[1]; }
  else      { a0 = bf2f(((const u16*)bout_raw)[0]); a1 = bf2f(((const u16*)bout_raw)[1]); }
  for (int i = 0; i < H_DIM; ++i){
    const float p = pooled[(size_t)s * HP + i];
    float w0, w1;
    if (isf32){ w0 = ((const float*)Wout_raw)[i]; w1 = ((const float*)Wout_raw)[H_DIM + i]; }
    else      { w0 = bf2f(((const u16*)Wout_raw)[i]); w1 = bf2f(((const u16*)Wout_raw)[H_DIM + i]); }
    a0 = fmaf(p, w0, a0);
    a1 = fmaf(p, w1, a1);
  }
  dout[s * 2 + 0] = a0;
  dout[s * 2 + 1] = a1;
}

// ---------------------------------------------------------------------------
extern "C" void kernel_launch(void* const* d_in, const int* in_sizes, int n_in,
                              void* d_out, int out_size, void* d_ws, size_t ws_size,
                              hipStream_t stream)
{
  const int* x  = (const int*)d_in[0];
  const void* emb  = d_in[1];
  const void* Wih  = d_in[2];
  const void* Whh  = d_in[3];
  const void* bih  = d_in[4];
  const void* bhh  = d_in[5];
  const void* Wout = d_in[6];
  const void* bout = d_in[7];
  float* out = (float*)d_out;

  char* ws = (char*)d_ws;
  u16*   Wpad   = (u16*)(ws + OFF_WPAD);
  float* biasp  = (float*)(ws + OFF_BIAS);
  int*   flag   = (int*)(ws + OFF_FLAG);
  u16*   hstate = (u16*)(ws + OFF_H);
  float* pooled = (float*)(ws + OFF_POOL);
  u16*   Whhp   = (u16*)(ws + OFF_WHH);
  float* xp     = (float*)(ws + OFF_XP);

  // choose chunk size (steps) so OFF_XP + CH*19*16*64*4 fits in ws_size
  const size_t per_step = (size_t)19 * 16 * 64 * 4;   // 77,824 B
  int CH = 16;
  const int cands[8] = {2048, 1024, 512, 256, 128, 64, 32, 16};
  for (int i = 0; i < 8; ++i){
    if ((size_t)OFF_XP + (size_t)cands[i] * per_step <= ws_size){ CH = cands[i]; break; }
  }
  const int nchunks = S_LEN / CH;

  detect<<<1, 256, 0, stream>>>((const u16*)emb, flag);
  prep<<<2432, 256, 0, stream>>>(Wih, Whh, bih, bhh, flag, Wpad, Whhp,
                                 biasp, pooled, (u32*)hstate);
  for (int k = 0; k < nchunks; ++k){
    const int s0 = k * CH;
    xp_gemm<<<CH, 256, 0, stream>>>(x, emb, flag, Wpad, biasp, xp, s0);
    recur<<<4, 256, 0, stream>>>(xp, Whhp, hstate, pooled, out, s0, CH);
  }
  outproj<<<16, 128, 0, stream>>>(pooled, Wout, bout, flag, out);
}

// Round 4
// 3073.446 us; speedup vs baseline: 1.0993x; 1.0993x over previous
//
#include <hip/hip_runtime.h>

typedef unsigned short u16;
typedef unsigned int   u32;
typedef unsigned long long u64;
typedef short s16x8 __attribute__((ext_vector_type(8)));
typedef float f32x4 __attribute__((ext_vector_type(4)));
typedef u32   u32x2 __attribute__((ext_vector_type(2)));
typedef _Float16 f16x8 __attribute__((ext_vector_type(8)));

#define S_LEN 2048
#define BATCH 64
#define H_DIM 300
#define HP    304   // padded output dim (W_ih rows)
#define KP    320   // padded contraction dim
#define HROW  328   // padded h row in LDS (f16 elems): 656 B = 41 x 16B units
#define BUF   5248  // u16 elems per h buffer = 16*328
#define XPS   20480 // xp elems (u16) per timestep = 64*320
#define HHS   20480 // hh elems (f32) per timestep = 64*320

// ws layout (bytes)
#define OFF_WPAD 0u         // 304*320*2 = 194,560  (bf16 W_ih [n][k])
#define OFF_BIAS 196608u    // 304*4               (f32 bih+bhh)
#define OFF_FLAG 198656u    // 4
#define OFF_H    200704u    // 64*320*2 = 40,960   (f16 h carry [b][k])
#define OFF_WHH  241664u    // 320*320*2 = 204,800 (f16 W_hh [n][k], zero-pad)
#define OFF_XP   458752u    // CH*64*320*2 (f16, [s][b][n])
// OFF_HH = OFF_XP + CH*40960  (f32, [s][b][n])

__device__ __forceinline__ float bf2f(u16 u){
  union { u32 i; float f; } v; v.i = ((u32)u) << 16; return v.f;
}
__device__ __forceinline__ u16 f2bf(float f){
  u32 i = __float_as_uint(f);
  u32 r = (i + 0x7fffu + ((i >> 16) & 1u)) >> 16;
  return (u16)r;
}
__device__ __forceinline__ u16 f2h(float f){
  union { _Float16 h; u16 u; } v; v.h = (_Float16)f; return v.u;
}
// packed f32x2 -> f16x2 (RTZ) as u32
__device__ __forceinline__ u32 pkh2(float a, float b){
  auto p = __builtin_amdgcn_cvt_pkrtz(a, b);
  union { decltype(p) h; u32 u; } v; v.h = p; return v.u;
}

#define SBAR0() __builtin_amdgcn_sched_barrier(0)
// LDS-only barrier: no vmcnt drain (xp prefetch / hh stores stay in flight).
#define BAR_LDS() do {                                        \
    __builtin_amdgcn_sched_barrier(0);                        \
    asm volatile("s_waitcnt lgkmcnt(0)" ::: "memory");        \
    __builtin_amdgcn_s_barrier();                             \
    __builtin_amdgcn_sched_barrier(0);                        \
  } while (0)

// ---------------------------------------------------------------------------
// detect: f32 vs bf16 input storage (bf16 emb exponents < 135 always).
// ---------------------------------------------------------------------------
__global__ __launch_bounds__(256) void detect(const u16* __restrict__ emb_raw,
                                              int* __restrict__ flag){
  __shared__ int big;
  if (threadIdx.x == 0) big = 0;
  __syncthreads();
  int loc = 0;
  for (int i = threadIdx.x; i < 1024; i += 256){
    const u32 e = ((u32)emb_raw[i] >> 7) & 0xFFu;
    if (e >= 135u) loc = 1;
  }
  if (loc) atomicOr(&big, 1);
  __syncthreads();
  if (threadIdx.x == 0) *flag = big;   // 1 = f32 inputs, 0 = bf16 inputs
}

// ---------------------------------------------------------------------------
// prep: bf16 W_ih pad [304][320]; fused f32 bias; f16 W_hh [320][320] zero-pad
// (rows/cols >= 300 are 0 -> pad tiles compute exact zeros); zero h carry.
// ---------------------------------------------------------------------------
__global__ __launch_bounds__(256) void prep(
    const void* __restrict__ Wih_raw, const void* __restrict__ Whh_raw,
    const void* __restrict__ bih_raw, const void* __restrict__ bhh_raw,
    const int* __restrict__ flag,
    u16* __restrict__ Wpad, u16* __restrict__ Whhp,
    float* __restrict__ biasp, u32* __restrict__ hstate32)
{
  const bool isf32 = (*flag != 0);
  const int idx = blockIdx.x * 256 + threadIdx.x;
  if (idx < BATCH * 160) hstate32[idx] = 0u;
  if (idx < 320 * 320){
    const int r = idx / 320, k = idx % 320;
    float w = 0.f;
    if (r < H_DIM && k < H_DIM){
      w = isf32 ? ((const float*)Whh_raw)[r * H_DIM + k]
                : bf2f(((const u16*)Whh_raw)[r * H_DIM + k]);
    }
    Whhp[idx] = f2h(w);
  }
  if (idx < HP * KP){
    const int n = idx / KP, k = idx % KP;
    u16 v = 0;
    if (n < H_DIM && k < H_DIM){
      v = isf32 ? f2bf(((const float*)Wih_raw)[n * H_DIM + k])
                : ((const u16*)Wih_raw)[n * H_DIM + k];
    }
    Wpad[idx] = v;
  }
  if (idx < HP){
    float bv = 0.f;
    if (idx < H_DIM){
      bv = isf32 ? (((const float*)bih_raw)[idx] + ((const float*)bhh_raw)[idx])
                 : (bf2f(((const u16*)bih_raw)[idx]) + bf2f(((const u16*)bhh_raw)[idx]));
    }
    biasp[idx] = bv;
  }
}

// ---------------------------------------------------------------------------
// xp_gemm: one block per timestep. D = Wih (A-slot, row=n) x emb (B-slot,
// col=b): lane (lm,lq) owns b=wave*16+lm, n = nt*16+lq*4+rr -> 4 consecutive
// n => one packed 8B store into xp[s][b][n] (f16). Bias folded. Zero-fills
// n 304..319 so recur's pad tile stays finite.
// ---------------------------------------------------------------------------
__global__ __launch_bounds__(256) void xp_gemm(
    const int* __restrict__ x, const void* __restrict__ emb_raw,
    const int* __restrict__ flag,
    const u16* __restrict__ Wpad, const float* __restrict__ biasp,
    u16* __restrict__ xp, int s0)
{
  __shared__ u16 A[64 * HROW];               // 42 KB, 656B rows (conflict-free)
  const bool isf32 = (*flag != 0);
  const int tid = threadIdx.x;
  const int srel = blockIdx.x;
  const int m0g = (s0 + srel) * BATCH;

  for (int t = tid; t < 64 * 82; t += 256){  // 82 u64 per row: 75 data + 7 pad
    const int row = t / 82, q = t - row * 82;
    u64 pk = 0;
    if (q < 75){
      const int tok = x[m0g + row];
      if (isf32){
        const float4 v = *(const float4*)((const float*)emb_raw + (size_t)tok * H_DIM + q * 4);
        pk = (u64)f2bf(v.x) | ((u64)f2bf(v.y) << 16)
           | ((u64)f2bf(v.z) << 32) | ((u64)f2bf(v.w) << 48);
      } else {
        pk = *(const u64*)((const u16*)emb_raw + (size_t)tok * H_DIM + q * 4);
      }
    }
    *(u64*)&A[row * HROW + q * 4] = pk;
  }
  __syncthreads();

  const int wave = tid >> 6, lane = tid & 63;
  const int lm = lane & 15, lq = lane >> 4;

  f32x4 acc[19];
#pragma unroll
  for (int nt = 0; nt < 19; ++nt) acc[nt] = (f32x4){0.f, 0.f, 0.f, 0.f};

#pragma unroll
  for (int ks = 0; ks < 10; ++ks){
    const int k = ks * 32 + lq * 8;
    const s16x8 bfrag = *(const s16x8*)&A[(wave * 16 + lm) * HROW + k];   // emb[b][k]
#pragma unroll
    for (int nt = 0; nt < 19; ++nt){
      const s16x8 afrag = *(const s16x8*)&Wpad[(size_t)(nt * 16 + lm) * KP + k]; // Wih[n][k]
      acc[nt] = __builtin_amdgcn_mfma_f32_16x16x32_bf16(afrag, bfrag, acc[nt], 0, 0, 0);
    }
  }

  u16* xrow = xp + ((size_t)srel * 64 + wave * 16 + lm) * 320;  // this lane's b
#pragma unroll
  for (int nt = 0; nt < 19; ++nt){
    const int n0 = nt * 16 + lq * 4;
    const f32x4 bv = *(const f32x4*)&biasp[n0];
    const float o0 = acc[nt][0] + bv[0], o1 = acc[nt][1] + bv[1];
    const float o2 = acc[nt][2] + bv[2], o3 = acc[nt][3] + bv[3];
    *(u32x2*)&xrow[n0] = (u32x2){pkh2(o0, o1), pkh2(o2, o3)};
  }
  *(u32x2*)&xrow[304 + lq * 4] = (u32x2){0u, 0u};   // pad tile stays finite
}

// ---------------------------------------------------------------------------
// recur: 4 blocks x 16 batches, 256 threads = 4 waves (1/SIMD, 512-VGPR
// budget). Per step: H_next(16x320) = relu(Whh x h + xp) via 50 MFMA
// 16x16x32 f16 per wave (wave w owns n-tiles 5w..5w+4; tile 19 is all-zero
// weights -> exact 0). Whh A-frags pinned resident via asm volatile loads
// (R3 lesson: plain loads got rematerialized into the loop, VGPR=184).
// h as f16 [b][HROW=328] double-buffered in LDS: B-frag = ds_read_b128,
// epilogue = ds_write_b64 -- both exactly conflict-free ((lm+lq)%8 uniform).
// xp f16 register-prefetched depth 2; relu'd h streamed f32 to hh[] for the
// separate maxout kernel (no atomics, no in-loop reduction). 1 barrier/step.
// ---------------------------------------------------------------------------
__global__ __launch_bounds__(256, 1) void recur(
    const u16* __restrict__ xp, const u16* __restrict__ Whhp,
    u32* __restrict__ hstate32, float* __restrict__ hh, int len)
{
  const int bblk = blockIdx.x;
  const int tid  = threadIdx.x;
  const int w  = tid >> 6, l = tid & 63;
  const int lm = l & 15,  lq = l >> 4;
  const int tW = w * 5;                    // first n-tile of this wave
  const int bg = bblk * 16 + lm;           // this lane's global batch

  __shared__ u16 hbuf[2 * BUF];            // 21 KB

  // ---- Whh A-frags: aq[i][ks] = Whh[(tW+i)*16+lm][ks*32+lq*8 ..+8]
  // asm volatile => cannot be rematerialized; stays in VGPRs.
  f16x8 aq[5][10];
#pragma unroll
  for (int i = 0; i < 5; ++i){
    const u16* rp = Whhp + (size_t)((tW + i) * 16 + lm) * 320 + lq * 8;
#pragma unroll
    for (int ks = 0; ks < 10; ++ks){
      asm volatile("global_load_dwordx4 %0, %1, off offset:%2"
                   : "=v"(aq[i][ks]) : "v"(rp), "n"(ks * 64) : "memory");
    }
  }

  // ---- h init: hstate [b][k] u32-pairs -> buf0 rows (incl zero pad)
  for (int idx = tid; idx < 16 * 164; idx += 256){
    const int b = idx / 164, q = idx - b * 164;
    u32 v = 0u;
    if (q < 160) v = hstate32[(size_t)(bblk * 16 + b) * 160 + q];
    ((u32*)hbuf)[b * 164 + q] = v;
  }

  const u16* xpp = xp + (size_t)bg * 320 + (tW * 16 + lq * 4);
  float*     hhp = hh + (size_t)bg * 320 + (tW * 16 + lq * 4);

  u32x2 xA[5], xB[5];
#pragma unroll
  for (int i = 0; i < 5; ++i) xA[i] = *(const u32x2*)(xpp + i * 16);
#pragma unroll
  for (int i = 0; i < 5; ++i) xB[i] = *(const u32x2*)(xpp + XPS + i * 16);
  const u16* xpre = xpp + 2 * (size_t)XPS;

  asm volatile("s_waitcnt vmcnt(0)" ::: "memory");
  __syncthreads();

#define STEP(XV, CURB, NXTB, PREP) do {                                       \
    f32x4 acc[5];                                                             \
    _Pragma("unroll")                                                         \
    for (int i = 0; i < 5; ++i){                                              \
      union { u32x2 u; __fp16 h[4]; } xu; xu.u = XV[i];                       \
      acc[i][0] = (float)xu.h[0]; acc[i][1] = (float)xu.h[1];                 \
      acc[i][2] = (float)xu.h[2]; acc[i][3] = (float)xu.h[3];                 \
    }                                                                         \
    _Pragma("unroll")                                                         \
    for (int i = 0; i < 5; ++i) XV[i] = *(const u32x2*)((PREP) + i * 16);     \
    _Pragma("unroll")                                                         \
    for (int ks = 0; ks < 10; ++ks){                                          \
      const f16x8 bfrag = *(const f16x8*)&hbuf[(CURB) + lm * HROW + ks * 32 + lq * 8]; \
      _Pragma("unroll")                                                       \
      for (int i = 0; i < 5; ++i)                                             \
        acc[i] = __builtin_amdgcn_mfma_f32_16x16x32_f16(aq[i][ks], bfrag, acc[i], 0, 0, 0); \
    }                                                                         \
    _Pragma("unroll")                                                         \
    for (int i = 0; i < 5; ++i){                                              \
      f32x4 hv;                                                               \
      hv[0] = fmaxf(acc[i][0], 0.f); hv[1] = fmaxf(acc[i][1], 0.f);           \
      hv[2] = fmaxf(acc[i][2], 0.f); hv[3] = fmaxf(acc[i][3], 0.f);           \
      *(f32x4*)(hhp + i * 16) = hv;                                           \
      *(u32x2*)&hbuf[(NXTB) + lm * HROW + ((tW + i) * 16 + lq * 4)] =         \
          (u32x2){pkh2(hv[0], hv[1]), pkh2(hv[2], hv[3])};                    \
    }                                                                         \
    hhp += HHS;                                                               \
    BAR_LDS();                                                                \
  } while (0)

  for (int t = 0; t < len; t += 2){
    const u16* pA = (t + 2 < len) ? xpre        : xpp;   // dummy ok (unused)
    const u16* pB = (t + 3 < len) ? (xpre + XPS) : xpp;
    STEP(xA, 0, BUF, pA);
    STEP(xB, BUF, 0, pB);
    xpre += 2 * (size_t)XPS;
  }
#undef STEP

  // ---- writeback carry (len even -> final h in buf0)
  for (int idx = tid; idx < 16 * 160; idx += 256){
    const int b = idx / 160, q = idx - b * 160;
    hstate32[(size_t)(bblk * 16 + b) * 160 + q] = ((u32*)hbuf)[b * 164 + q];
  }
}

// ---------------------------------------------------------------------------
// maxout: one block per timestep. Max over 64 batches of hh[s][b][n] (f32),
// then the 2-wide output projection; also emits hT rows at s == S_LEN-1.
// ---------------------------------------------------------------------------
__global__ __launch_bounds__(320) void maxout(
    const float* __restrict__ hh, const void* __restrict__ Wout_raw,
    const void* __restrict__ bout_raw, const int* __restrict__ flag,
    float* __restrict__ dout, int s0)
{
  const int srel = blockIdx.x, s = s0 + srel;
  const int n = threadIdx.x;               // 0..319
  __shared__ float mv[320];

  const float* hp = hh + (size_t)srel * HHS + n;
  const bool wrT = (s == S_LEN - 1) && (n < H_DIM);
  float m = 0.f;
  for (int b = 0; b < 64; ++b){
    const float v = hp[b * 320];
    m = fmaxf(m, v);
    if (wrT) dout[S_LEN * 2 + (size_t)b * H_DIM + n] = v;
  }
  mv[n] = m;
  __syncthreads();

  if (threadIdx.x < 64){
    const bool isf32 = (*flag != 0);
    const int lidx = threadIdx.x;
    float a0 = 0.f, a1 = 0.f;
#pragma unroll
    for (int j = 0; j < 5; ++j){
      const int nn = lidx * 5 + j;
      if (nn < H_DIM){
        float w0, w1;
        if (isf32){ w0 = ((const float*)Wout_raw)[nn]; w1 = ((const float*)Wout_raw)[H_DIM + nn]; }
        else      { w0 = bf2f(((const u16*)Wout_raw)[nn]); w1 = bf2f(((const u16*)Wout_raw)[H_DIM + nn]); }
        a0 = fmaf(mv[nn], w0, a0);
        a1 = fmaf(mv[nn], w1, a1);
      }
    }
    for (int off = 32; off; off >>= 1){
      a0 += __shfl_down(a0, off);
      a1 += __shfl_down(a1, off);
    }
    if (lidx == 0){
      float b0, b1;
      const bool isf = (*flag != 0);
      if (isf){ b0 = ((const float*)bout_raw)[0]; b1 = ((const float*)bout_raw)[1]; }
      else    { b0 = bf2f(((const u16*)bout_raw)[0]); b1 = bf2f(((const u16*)bout_raw)[1]); }
      dout[s * 2 + 0] = a0 + b0;
      dout[s * 2 + 1] = a1 + b1;
    }
  }
}

// ---------------------------------------------------------------------------
extern "C" void kernel_launch(void* const* d_in, const int* in_sizes, int n_in,
                              void* d_out, int out_size, void* d_ws, size_t ws_size,
                              hipStream_t stream)
{
  const int* x  = (const int*)d_in[0];
  const void* emb  = d_in[1];
  const void* Wih  = d_in[2];
  const void* Whh  = d_in[3];
  const void* bih  = d_in[4];
  const void* bhh  = d_in[5];
  const void* Wout = d_in[6];
  const void* bout = d_in[7];
  float* out = (float*)d_out;

  char* ws = (char*)d_ws;
  u16*   Wpad     = (u16*)(ws + OFF_WPAD);
  float* biasp    = (float*)(ws + OFF_BIAS);
  int*   flag     = (int*)(ws + OFF_FLAG);
  u32*   hstate32 = (u32*)(ws + OFF_H);
  u16*   Whhp     = (u16*)(ws + OFF_WHH);
  u16*   xpu      = (u16*)(ws + OFF_XP);

  // choose chunk size: xp (CH*40,960 B) + hh (CH*81,920 B) must fit
  int CH = 128;
  const int cands[5] = {2048, 1024, 512, 256, 128};
  for (int i = 0; i < 5; ++i){
    if ((size_t)OFF_XP + (size_t)cands[i] * (40960u + 81920u) <= ws_size){ CH = cands[i]; break; }
  }
  const int nchunks = S_LEN / CH;
  float* hh = (float*)(ws + OFF_XP + (size_t)CH * 40960u);

  detect<<<1, 256, 0, stream>>>((const u16*)emb, flag);
  prep<<<400, 256, 0, stream>>>(Wih, Whh, bih, bhh, flag, Wpad, Whhp,
                                biasp, hstate32);
  for (int k = 0; k < nchunks; ++k){
    const int s0 = k * CH;
    xp_gemm<<<CH, 256, 0, stream>>>(x, emb, flag, Wpad, biasp, xpu, s0);
    recur<<<4, 256, 0, stream>>>(xpu, Whhp, hstate32, hh, CH);
    maxout<<<CH, 320, 0, stream>>>(hh, Wout, bout, flag, out, s0);
  }
}

// Round 7
// 2578.335 us; speedup vs baseline: 1.3104x; 1.1920x over previous
//
#include <hip/hip_runtime.h>

typedef unsigned short u16;
typedef unsigned int   u32;
typedef unsigned long long u64;
typedef short s16x8 __attribute__((ext_vector_type(8)));
typedef float f32x4 __attribute__((ext_vector_type(4)));
typedef u32   u32x2 __attribute__((ext_vector_type(2)));
typedef _Float16 f16x8 __attribute__((ext_vector_type(8)));

#define S_LEN 2048
#define BATCH 64
#define H_DIM 300
#define HP    304   // padded output dim (W_ih rows)
#define KP    320   // padded contraction dim
#define HROW  328   // padded h row in LDS (f16 elems): 656 B
#define BUF   5248  // u16 elems per h buffer = 16*328
#define XPS   20480 // xp elems (u16) per timestep = 64*320
#define HHS   20480 // hh elems (f32) per timestep = 64*320

// ws layout (bytes)
#define OFF_WPAD 0u         // 304*320*2 = 194,560  (bf16 W_ih [n][k])
#define OFF_BIAS 196608u    // 304*4               (f32 bih+bhh)
#define OFF_FLAG 198656u    // 4
#define OFF_H    200704u    // 64*320*2 = 40,960   (f16 h carry [b][k])
#define OFF_WHH  241664u    // 320*320*2 = 204,800 (f16 W_hh [n][k], zero-pad)
#define OFF_XP   458752u    // CH*64*320*2 (f16, [s][b][n])
// OFF_HH = OFF_XP + CH*40960  (f32, [s][b][n])

__device__ __forceinline__ float bf2f(u16 u){
  union { u32 i; float f; } v; v.i = ((u32)u) << 16; return v.f;
}
__device__ __forceinline__ u16 f2bf(float f){
  u32 i = __float_as_uint(f);
  u32 r = (i + 0x7fffu + ((i >> 16) & 1u)) >> 16;
  return (u16)r;
}
__device__ __forceinline__ u16 f2h(float f){
  union { _Float16 h; u16 u; } v; v.h = (_Float16)f; return v.u;
}
// packed f32x2 -> f16x2 (RTZ) as u32
__device__ __forceinline__ u32 pkh2(float a, float b){
  auto p = __builtin_amdgcn_cvt_pkrtz(a, b);
  union { decltype(p) h; u32 u; } v; v.h = p; return v.u;
}

#define SBAR0() __builtin_amdgcn_sched_barrier(0)
// LDS-only barrier: no vmcnt drain (xp prefetch / hh stores stay in flight).
#define BAR_LDS() do {                                        \
    __builtin_amdgcn_sched_barrier(0);                        \
    asm volatile("s_waitcnt lgkmcnt(0)" ::: "memory");        \
    __builtin_amdgcn_s_barrier();                             \
    __builtin_amdgcn_sched_barrier(0);                        \
  } while (0)

// ---------------------------------------------------------------------------
// detect: f32 vs bf16 input storage (bf16 emb exponents < 135 always).
// ---------------------------------------------------------------------------
__global__ __launch_bounds__(256) void detect(const u16* __restrict__ emb_raw,
                                              int* __restrict__ flag){
  __shared__ int big;
  if (threadIdx.x == 0) big = 0;
  __syncthreads();
  int loc = 0;
  for (int i = threadIdx.x; i < 1024; i += 256){
    const u32 e = ((u32)emb_raw[i] >> 7) & 0xFFu;
    if (e >= 135u) loc = 1;
  }
  if (loc) atomicOr(&big, 1);
  __syncthreads();
  if (threadIdx.x == 0) *flag = big;   // 1 = f32 inputs, 0 = bf16 inputs
}

// ---------------------------------------------------------------------------
// prep: bf16 W_ih pad [304][320]; fused f32 bias; f16 W_hh [320][320] zero-pad
// (rows/cols >= 300 are 0 -> pad tiles compute exact zeros); zero h carry.
// ---------------------------------------------------------------------------
__global__ __launch_bounds__(256) void prep(
    const void* __restrict__ Wih_raw, const void* __restrict__ Whh_raw,
    const void* __restrict__ bih_raw, const void* __restrict__ bhh_raw,
    const int* __restrict__ flag,
    u16* __restrict__ Wpad, u16* __restrict__ Whhp,
    float* __restrict__ biasp, u32* __restrict__ hstate32)
{
  const bool isf32 = (*flag != 0);
  const int idx = blockIdx.x * 256 + threadIdx.x;
  if (idx < BATCH * 160) hstate32[idx] = 0u;
  if (idx < 320 * 320){
    const int r = idx / 320, k = idx % 320;
    float w = 0.f;
    if (r < H_DIM && k < H_DIM){
      w = isf32 ? ((const float*)Whh_raw)[r * H_DIM + k]
                : bf2f(((const u16*)Whh_raw)[r * H_DIM + k]);
    }
    Whhp[idx] = f2h(w);
  }
  if (idx < HP * KP){
    const int n = idx / KP, k = idx % KP;
    u16 v = 0;
    if (n < H_DIM && k < H_DIM){
      v = isf32 ? f2bf(((const float*)Wih_raw)[n * H_DIM + k])
                : ((const u16*)Wih_raw)[n * H_DIM + k];
    }
    Wpad[idx] = v;
  }
  if (idx < HP){
    float bv = 0.f;
    if (idx < H_DIM){
      bv = isf32 ? (((const float*)bih_raw)[idx] + ((const float*)bhh_raw)[idx])
                 : (bf2f(((const u16*)bih_raw)[idx]) + bf2f(((const u16*)bhh_raw)[idx]));
    }
    biasp[idx] = bv;
  }
}

// ---------------------------------------------------------------------------
// xp_gemm: one block per timestep. D = Wih (A-slot, row=n) x emb (B-slot,
// col=b): lane (lm,lq) owns b=wave*16+lm, n = nt*16+lq*4+rr -> one packed
// 8B store into xp[s][b][n] (f16). Bias folded. Zero-fills n 304..319.
// ---------------------------------------------------------------------------
__global__ __launch_bounds__(256) void xp_gemm(
    const int* __restrict__ x, const void* __restrict__ emb_raw,
    const int* __restrict__ flag,
    const u16* __restrict__ Wpad, const float* __restrict__ biasp,
    u16* __restrict__ xp, int s0)
{
  __shared__ u16 A[64 * HROW];               // 42 KB
  const bool isf32 = (*flag != 0);
  const int tid = threadIdx.x;
  const int srel = blockIdx.x;
  const int m0g = (s0 + srel) * BATCH;

  for (int t = tid; t < 64 * 82; t += 256){  // 82 u64 per row: 75 data + 7 pad
    const int row = t / 82, q = t - row * 82;
    u64 pk = 0;
    if (q < 75){
      const int tok = x[m0g + row];
      if (isf32){
        const float4 v = *(const float4*)((const float*)emb_raw + (size_t)tok * H_DIM + q * 4);
        pk = (u64)f2bf(v.x) | ((u64)f2bf(v.y) << 16)
           | ((u64)f2bf(v.z) << 32) | ((u64)f2bf(v.w) << 48);
      } else {
        pk = *(const u64*)((const u16*)emb_raw + (size_t)tok * H_DIM + q * 4);
      }
    }
    *(u64*)&A[row * HROW + q * 4] = pk;
  }
  __syncthreads();

  const int wave = tid >> 6, lane = tid & 63;
  const int lm = lane & 15, lq = lane >> 4;

  f32x4 acc[19];
#pragma unroll
  for (int nt = 0; nt < 19; ++nt) acc[nt] = (f32x4){0.f, 0.f, 0.f, 0.f};

#pragma unroll
  for (int ks = 0; ks < 10; ++ks){
    const int k = ks * 32 + lq * 8;
    const s16x8 bfrag = *(const s16x8*)&A[(wave * 16 + lm) * HROW + k];   // emb[b][k]
#pragma unroll
    for (int nt = 0; nt < 19; ++nt){
      const s16x8 afrag = *(const s16x8*)&Wpad[(size_t)(nt * 16 + lm) * KP + k]; // Wih[n][k]
      acc[nt] = __builtin_amdgcn_mfma_f32_16x16x32_bf16(afrag, bfrag, acc[nt], 0, 0, 0);
    }
  }

  u16* xrow = xp + ((size_t)srel * 64 + wave * 16 + lm) * 320;  // this lane's b
#pragma unroll
  for (int nt = 0; nt < 19; ++nt){
    const int n0 = nt * 16 + lq * 4;
    const f32x4 bv = *(const f32x4*)&biasp[n0];
    const float o0 = acc[nt][0] + bv[0], o1 = acc[nt][1] + bv[1];
    const float o2 = acc[nt][2] + bv[2], o3 = acc[nt][3] + bv[3];
    *(u32x2*)&xrow[n0] = (u32x2){pkh2(o0, o1), pkh2(o2, o3)};
  }
  *(u32x2*)&xrow[304 + lq * 4] = (u32x2){0u, 0u};   // pad tile stays finite
}

// ---------------------------------------------------------------------------
// recur: minimal diff from the verified R4 kernel (which was per-CU mem-BW
// bound: 30.7 KB/step/block at ~10 B/cy/CU = 3072 cy/step on 4 CUs).
// Change: 16 blocks x 4 batches (was 4 x 16) -> same aggregate stream spread
// over 4x CUs, per-block 7.7 KB/step (~770 cy). Batch rows 4..15 of the LDS
// h buffer are pad: they re-simulate real batches (same xp, zero h init) --
// finite, never stored to hh (store is act-predicated; blocks write disjoint
// b-slices of hh). Everything else identical to R4: Whh A-frags pinned via
// asm volatile loads, h f16 [16][HROW] double-buffered, depth-2 xp prefetch,
// 1 lgkm-only barrier/step, hh f32 stream consumed by maxout.
// ---------------------------------------------------------------------------
__global__ __launch_bounds__(256, 1) void recur(
    const u16* __restrict__ xp, const u16* __restrict__ Whhp,
    u32* __restrict__ hstate32, float* __restrict__ hh, int len)
{
  const int bblk = blockIdx.x;             // 0..15
  const int tid  = threadIdx.x;
  const int w  = tid >> 6, l = tid & 63;
  const int lm = l & 15,  lq = l >> 4;
  const int tW = w * 5;                    // first n-tile of this wave
  const bool act = (lm < 4);               // lanes owning a real batch
  const int bg = bblk * 4 + (lm & 3);      // this lane's global batch

  __shared__ u16 hbuf[2 * BUF];            // 21 KB

  // ---- Whh A-frags: aq[i][ks] = Whh[(tW+i)*16+lm][ks*32+lq*8 ..+8]
  // asm volatile => cannot be rematerialized; stays resident (R3 lesson).
  f16x8 aq[5][10];
#pragma unroll
  for (int i = 0; i < 5; ++i){
    const u16* rp = Whhp + (size_t)((tW + i) * 16 + lm) * 320 + lq * 8;
#pragma unroll
    for (int ks = 0; ks < 10; ++ks){
      asm volatile("global_load_dwordx4 %0, %1, off offset:%2"
                   : "=v"(aq[i][ks]) : "v"(rp), "n"(ks * 64) : "memory");
    }
  }

  // ---- zero both h buffers, then fill rows 0..3 of buf0 from carry
  for (int idx = tid; idx < 2 * 16 * 164; idx += 256) ((u32*)hbuf)[idx] = 0u;
  __syncthreads();
  for (int idx = tid; idx < 4 * 160; idx += 256){
    const int b = idx / 160, q = idx - b * 160;
    ((u32*)hbuf)[b * 164 + q] = hstate32[(size_t)(bblk * 4 + b) * 160 + q];
  }

  const u16* xpp = xp + (size_t)bg * 320 + (tW * 16 + lq * 4);
  float*     hhp = hh + (size_t)bg * 320 + (tW * 16 + lq * 4);

  u32x2 xA[5], xB[5];
#pragma unroll
  for (int i = 0; i < 5; ++i) xA[i] = *(const u32x2*)(xpp + i * 16);
#pragma unroll
  for (int i = 0; i < 5; ++i) xB[i] = *(const u32x2*)(xpp + XPS + i * 16);
  const u16* xpre = xpp + 2 * (size_t)XPS;

  asm volatile("s_waitcnt vmcnt(0)" ::: "memory");
  __syncthreads();

#define STEP(XV, CURB, NXTB, PREP) do {                                       \
    f32x4 acc[5];                                                             \
    _Pragma("unroll")                                                         \
    for (int i = 0; i < 5; ++i){                                              \
      union { u32x2 u; __fp16 h[4]; } xu; xu.u = XV[i];                       \
      acc[i][0] = (float)xu.h[0]; acc[i][1] = (float)xu.h[1];                 \
      acc[i][2] = (float)xu.h[2]; acc[i][3] = (float)xu.h[3];                 \
    }                                                                         \
    _Pragma("unroll")                                                         \
    for (int i = 0; i < 5; ++i) XV[i] = *(const u32x2*)((PREP) + i * 16);     \
    _Pragma("unroll")                                                         \
    for (int ks = 0; ks < 10; ++ks){                                          \
      const f16x8 bfrag = *(const f16x8*)&hbuf[(CURB) + lm * HROW + ks * 32 + lq * 8]; \
      _Pragma("unroll")                                                       \
      for (int i = 0; i < 5; ++i)                                             \
        acc[i] = __builtin_amdgcn_mfma_f32_16x16x32_f16(aq[i][ks], bfrag, acc[i], 0, 0, 0); \
    }                                                                         \
    _Pragma("unroll")                                                         \
    for (int i = 0; i < 5; ++i){                                              \
      f32x4 hv;                                                               \
      hv[0] = fmaxf(acc[i][0], 0.f); hv[1] = fmaxf(acc[i][1], 0.f);           \
      hv[2] = fmaxf(acc[i][2], 0.f); hv[3] = fmaxf(acc[i][3], 0.f);           \
      if (act) *(f32x4*)(hhp + i * 16) = hv;                                  \
      *(u32x2*)&hbuf[(NXTB) + lm * HROW + ((tW + i) * 16 + lq * 4)] =         \
          (u32x2){pkh2(hv[0], hv[1]), pkh2(hv[2], hv[3])};                    \
    }                                                                         \
    hhp += HHS;                                                               \
    BAR_LDS();                                                                \
  } while (0)

  for (int t = 0; t < len; t += 2){
    const u16* pA = (t + 2 < len) ? xpre         : xpp;   // tail: dummy (unused)
    const u16* pB = (t + 3 < len) ? (xpre + XPS) : xpp;
    STEP(xA, 0, BUF, pA);
    STEP(xB, BUF, 0, pB);
    xpre += 2 * (size_t)XPS;
  }
#undef STEP

  // ---- writeback carry (len even -> final h in buf0), rows 0..3
  for (int idx = tid; idx < 4 * 160; idx += 256){
    const int b = idx / 160, q = idx - b * 160;
    hstate32[(size_t)(bblk * 4 + b) * 160 + q] = ((u32*)hbuf)[b * 164 + q];
  }
}

// ---------------------------------------------------------------------------
// maxout: one block per timestep. Max over 64 batches of hh[s][b][n] (f32),
// then the 2-wide output projection; also emits hT rows at s == S_LEN-1.
// (unchanged from the verified R4 kernel)
// ---------------------------------------------------------------------------
__global__ __launch_bounds__(320) void maxout(
    const float* __restrict__ hh, const void* __restrict__ Wout_raw,
    const void* __restrict__ bout_raw, const int* __restrict__ flag,
    float* __restrict__ dout, int s0)
{
  const int srel = blockIdx.x, s = s0 + srel;
  const int n = threadIdx.x;               // 0..319
  __shared__ float mv[320];

  const float* hp = hh + (size_t)srel * HHS + n;
  const bool wrT = (s == S_LEN - 1) && (n < H_DIM);
  float m = 0.f;
  for (int b = 0; b < 64; ++b){
    const float v = hp[b * 320];
    m = fmaxf(m, v);
    if (wrT) dout[S_LEN * 2 + (size_t)b * H_DIM + n] = v;
  }
  mv[n] = m;
  __syncthreads();

  if (threadIdx.x < 64){
    const bool isf32 = (*flag != 0);
    const int lidx = threadIdx.x;
    float a0 = 0.f, a1 = 0.f;
#pragma unroll
    for (int j = 0; j < 5; ++j){
      const int nn = lidx * 5 + j;
      if (nn < H_DIM){
        float w0, w1;
        if (isf32){ w0 = ((const float*)Wout_raw)[nn]; w1 = ((const float*)Wout_raw)[H_DIM + nn]; }
        else      { w0 = bf2f(((const u16*)Wout_raw)[nn]); w1 = bf2f(((const u16*)Wout_raw)[H_DIM + nn]); }
        a0 = fmaf(mv[nn], w0, a0);
        a1 = fmaf(mv[nn], w1, a1);
      }
    }
    for (int off = 32; off; off >>= 1){
      a0 += __shfl_down(a0, off);
      a1 += __shfl_down(a1, off);
    }
    if (lidx == 0){
      float b0, b1;
      if (isf32){ b0 = ((const float*)bout_raw)[0]; b1 = ((const float*)bout_raw)[1]; }
      else      { b0 = bf2f(((const u16*)bout_raw)[0]); b1 = bf2f(((const u16*)bout_raw)[1]); }
      dout[s * 2 + 0] = a0 + b0;
      dout[s * 2 + 1] = a1 + b1;
    }
  }
}

// ---------------------------------------------------------------------------
extern "C" void kernel_launch(void* const* d_in, const int* in_sizes, int n_in,
                              void* d_out, int out_size, void* d_ws, size_t ws_size,
                              hipStream_t stream)
{
  const int* x  = (const int*)d_in[0];
  const void* emb  = d_in[1];
  const void* Wih  = d_in[2];
  const void* Whh  = d_in[3];
  const void* bih  = d_in[4];
  const void* bhh  = d_in[5];
  const void* Wout = d_in[6];
  const void* bout = d_in[7];
  float* out = (float*)d_out;

  char* ws = (char*)d_ws;
  u16*   Wpad     = (u16*)(ws + OFF_WPAD);
  float* biasp    = (float*)(ws + OFF_BIAS);
  int*   flag     = (int*)(ws + OFF_FLAG);
  u32*   hstate32 = (u32*)(ws + OFF_H);
  u16*   Whhp     = (u16*)(ws + OFF_WHH);
  u16*   xpu      = (u16*)(ws + OFF_XP);

  // chunk size: xp (CH*40,960 B) + hh (CH*81,920 B) must fit
  int CH = 128;
  const int cands[5] = {2048, 1024, 512, 256, 128};
  for (int i = 0; i < 5; ++i){
    if ((size_t)OFF_XP + (size_t)cands[i] * (40960u + 81920u) <= ws_size){ CH = cands[i]; break; }
  }
  const int nchunks = S_LEN / CH;
  float* hh = (float*)(ws + OFF_XP + (size_t)CH * 40960u);

  detect<<<1, 256, 0, stream>>>((const u16*)emb, flag);
  prep<<<400, 256, 0, stream>>>(Wih, Whh, bih, bhh, flag, Wpad, Whhp,
                                biasp, hstate32);
  for (int k = 0; k < nchunks; ++k){
    const int s0 = k * CH;
    xp_gemm<<<CH, 256, 0, stream>>>(x, emb, flag, Wpad, biasp, xpu, s0);
    recur<<<16, 256, 0, stream>>>(xpu, Whhp, hstate32, hh, CH);
    maxout<<<CH, 320, 0, stream>>>(hh, Wout, bout, flag, out, s0);
  }
}

// Round 9
// 2570.141 us; speedup vs baseline: 1.3146x; 1.0032x over previous
//
#include <hip/hip_runtime.h>

typedef unsigned short u16;
typedef unsigned int   u32;
typedef unsigned long long u64;
typedef short s16x8 __attribute__((ext_vector_type(8)));
typedef float f32x4 __attribute__((ext_vector_type(4)));
typedef u32   u32x2 __attribute__((ext_vector_type(2)));
typedef _Float16 f16x8 __attribute__((ext_vector_type(8)));

#define S_LEN 2048
#define BATCH 64
#define H_DIM 300
#define HP    304   // padded output dim (W_ih rows)
#define KP    320   // padded contraction dim
#define HROW  328   // padded h row in LDS (f16 elems): 656 B
#define BUF   5248  // u16 elems per h buffer = 16*328
#define XPS   20480 // xp elems (u16) per timestep = 64*320
#define HHS   20480 // hh elems (f32) per timestep = 64*320

// ws layout (bytes)
#define OFF_WPAD 0u         // 304*320*2 = 194,560  (bf16 W_ih [n][k])
#define OFF_BIAS 196608u    // 304*4               (f32 bih+bhh)
#define OFF_FLAG 198656u    // 4
#define OFF_H    200704u    // 64*320*2 = 40,960   (f16 h carry [b][k])
#define OFF_WHH  241664u    // 320*320*2 = 204,800 (f16 W_hh [n][k], zero-pad)
#define OFF_XP   458752u    // CH*64*320*2 (f16, [s][b][n])
// OFF_HH = OFF_XP + CH*40960  (f32, [s][b][n])

__device__ __forceinline__ float bf2f(u16 u){
  union { u32 i; float f; } v; v.i = ((u32)u) << 16; return v.f;
}
__device__ __forceinline__ u16 f2bf(float f){
  u32 i = __float_as_uint(f);
  u32 r = (i + 0x7fffu + ((i >> 16) & 1u)) >> 16;
  return (u16)r;
}
__device__ __forceinline__ u16 f2h(float f){
  union { _Float16 h; u16 u; } v; v.h = (_Float16)f; return v.u;
}
// packed f32x2 -> f16x2 (RTZ) as u32
__device__ __forceinline__ u32 pkh2(float a, float b){
  auto p = __builtin_amdgcn_cvt_pkrtz(a, b);
  union { decltype(p) h; u32 u; } v; v.h = p; return v.u;
}

#define SBAR0() __builtin_amdgcn_sched_barrier(0)
// LDS-only barrier: no vmcnt drain (xp prefetch / hh stores stay in flight).
#define BAR_LDS() do {                                        \
    __builtin_amdgcn_sched_barrier(0);                        \
    asm volatile("s_waitcnt lgkmcnt(0)" ::: "memory");        \
    __builtin_amdgcn_s_barrier();                             \
    __builtin_amdgcn_sched_barrier(0);                        \
  } while (0)

// ---------------------------------------------------------------------------
// detect: f32 vs bf16 input storage (bf16 emb exponents < 135 always).
// ---------------------------------------------------------------------------
__global__ __launch_bounds__(256) void detect(const u16* __restrict__ emb_raw,
                                              int* __restrict__ flag){
  __shared__ int big;
  if (threadIdx.x == 0) big = 0;
  __syncthreads();
  int loc = 0;
  for (int i = threadIdx.x; i < 1024; i += 256){
    const u32 e = ((u32)emb_raw[i] >> 7) & 0xFFu;
    if (e >= 135u) loc = 1;
  }
  if (loc) atomicOr(&big, 1);
  __syncthreads();
  if (threadIdx.x == 0) *flag = big;   // 1 = f32 inputs, 0 = bf16 inputs
}

// ---------------------------------------------------------------------------
// prep: bf16 W_ih pad [304][320]; fused f32 bias; f16 W_hh [320][320] zero-pad
// (rows/cols >= 300 are 0 -> pad tiles compute exact zeros); zero h carry.
// ---------------------------------------------------------------------------
__global__ __launch_bounds__(256) void prep(
    const void* __restrict__ Wih_raw, const void* __restrict__ Whh_raw,
    const void* __restrict__ bih_raw, const void* __restrict__ bhh_raw,
    const int* __restrict__ flag,
    u16* __restrict__ Wpad, u16* __restrict__ Whhp,
    float* __restrict__ biasp, u32* __restrict__ hstate32)
{
  const bool isf32 = (*flag != 0);
  const int idx = blockIdx.x * 256 + threadIdx.x;
  if (idx < BATCH * 160) hstate32[idx] = 0u;
  if (idx < 320 * 320){
    const int r = idx / 320, k = idx % 320;
    float w = 0.f;
    if (r < H_DIM && k < H_DIM){
      w = isf32 ? ((const float*)Whh_raw)[r * H_DIM + k]
                : bf2f(((const u16*)Whh_raw)[r * H_DIM + k]);
    }
    Whhp[idx] = f2h(w);
  }
  if (idx < HP * KP){
    const int n = idx / KP, k = idx % KP;
    u16 v = 0;
    if (n < H_DIM && k < H_DIM){
      v = isf32 ? f2bf(((const float*)Wih_raw)[n * H_DIM + k])
                : ((const u16*)Wih_raw)[n * H_DIM + k];
    }
    Wpad[idx] = v;
  }
  if (idx < HP){
    float bv = 0.f;
    if (idx < H_DIM){
      bv = isf32 ? (((const float*)bih_raw)[idx] + ((const float*)bhh_raw)[idx])
                 : (bf2f(((const u16*)bih_raw)[idx]) + bf2f(((const u16*)bhh_raw)[idx]));
    }
    biasp[idx] = bv;
  }
}

// ---------------------------------------------------------------------------
// xp_gemm: one block per timestep. D = Wih (A-slot, row=n) x emb (B-slot,
// col=b): lane (lm,lq) owns b=wave*16+lm, n = nt*16+lq*4+rr -> one packed
// 8B store into xp[s][b][n] (f16). Bias folded. Zero-fills n 304..319.
// ---------------------------------------------------------------------------
__global__ __launch_bounds__(256) void xp_gemm(
    const int* __restrict__ x, const void* __restrict__ emb_raw,
    const int* __restrict__ flag,
    const u16* __restrict__ Wpad, const float* __restrict__ biasp,
    u16* __restrict__ xp, int s0)
{
  __shared__ u16 A[64 * HROW];               // 42 KB
  const bool isf32 = (*flag != 0);
  const int tid = threadIdx.x;
  const int srel = blockIdx.x;
  const int m0g = (s0 + srel) * BATCH;

  for (int t = tid; t < 64 * 82; t += 256){  // 82 u64 per row: 75 data + 7 pad
    const int row = t / 82, q = t - row * 82;
    u64 pk = 0;
    if (q < 75){
      const int tok = x[m0g + row];
      if (isf32){
        const float4 v = *(const float4*)((const float*)emb_raw + (size_t)tok * H_DIM + q * 4);
        pk = (u64)f2bf(v.x) | ((u64)f2bf(v.y) << 16)
           | ((u64)f2bf(v.z) << 32) | ((u64)f2bf(v.w) << 48);
      } else {
        pk = *(const u64*)((const u16*)emb_raw + (size_t)tok * H_DIM + q * 4);
      }
    }
    *(u64*)&A[row * HROW + q * 4] = pk;
  }
  __syncthreads();

  const int wave = tid >> 6, lane = tid & 63;
  const int lm = lane & 15, lq = lane >> 4;

  f32x4 acc[19];
#pragma unroll
  for (int nt = 0; nt < 19; ++nt) acc[nt] = (f32x4){0.f, 0.f, 0.f, 0.f};

#pragma unroll
  for (int ks = 0; ks < 10; ++ks){
    const int k = ks * 32 + lq * 8;
    const s16x8 bfrag = *(const s16x8*)&A[(wave * 16 + lm) * HROW + k];   // emb[b][k]
#pragma unroll
    for (int nt = 0; nt < 19; ++nt){
      const s16x8 afrag = *(const s16x8*)&Wpad[(size_t)(nt * 16 + lm) * KP + k]; // Wih[n][k]
      acc[nt] = __builtin_amdgcn_mfma_f32_16x16x32_bf16(afrag, bfrag, acc[nt], 0, 0, 0);
    }
  }

  u16* xrow = xp + ((size_t)srel * 64 + wave * 16 + lm) * 320;  // this lane's b
#pragma unroll
  for (int nt = 0; nt < 19; ++nt){
    const int n0 = nt * 16 + lq * 4;
    const f32x4 bv = *(const f32x4*)&biasp[n0];
    const float o0 = acc[nt][0] + bv[0], o1 = acc[nt][1] + bv[1];
    const float o2 = acc[nt][2] + bv[2], o3 = acc[nt][3] + bv[3];
    *(u32x2*)&xrow[n0] = (u32x2){pkh2(o0, o1), pkh2(o2, o3)};
  }
  *(u32x2*)&xrow[304 + lq * 4] = (u32x2){0u, 0u};   // pad tile stays finite
}

// ---------------------------------------------------------------------------
// recur: identical structure to the verified R7 kernel (16 blocks x 4
// batches, 4 waves, h double-buffered in LDS, depth-2 xp prefetch, 1
// lgkm-only barrier/step). Two changes driven by R7's VGPR=144 counter
// (the 200-VGPR Whh set was spilled/remat'd -> ~200 dwords/lane/step of
// scratch traffic at 1 wave/SIMD):
//  1) aq loaded with PLAIN loads (the asm-volatile load pattern is
//     waitcnt-unsafe under spill -- suspected R8 fault source; removed).
//  2) amdgpu_waves_per_eu(1,1): max 1 wave/EU removes the allocator's
//     occupancy incentive to remat/spill -- full 512-VGPR budget, aq
//     (200 regs) stays genuinely resident.
// ---------------------------------------------------------------------------
__global__ __launch_bounds__(256, 1)
__attribute__((amdgpu_waves_per_eu(1, 1)))
void recur(
    const u16* __restrict__ xp, const u16* __restrict__ Whhp,
    u32* __restrict__ hstate32, float* __restrict__ hh, int len)
{
  const int bblk = blockIdx.x;             // 0..15
  const int tid  = threadIdx.x;
  const int w  = tid >> 6, l = tid & 63;
  const int lm = l & 15,  lq = l >> 4;
  const int tW = w * 5;                    // first n-tile of this wave
  const bool act = (lm < 4);               // lanes owning a real batch
  const int bg = bblk * 4 + (lm & 3);      // this lane's global batch

  __shared__ u16 hbuf[2 * BUF];            // 21 KB

  // ---- Whh A-frags: aq[i][ks] = Whh[(tW+i)*16+lm][ks*32+lq*8 ..+8]
  // plain loads; residency guaranteed by waves_per_eu(1,1) budget.
  f16x8 aq[5][10];
#pragma unroll
  for (int i = 0; i < 5; ++i){
    const u16* rp = Whhp + (size_t)((tW + i) * 16 + lm) * 320 + lq * 8;
#pragma unroll
    for (int ks = 0; ks < 10; ++ks)
      aq[i][ks] = *(const f16x8*)(rp + ks * 32);
  }

  // ---- zero both h buffers, then fill rows 0..3 of buf0 from carry
  for (int idx = tid; idx < 2 * 16 * 164; idx += 256) ((u32*)hbuf)[idx] = 0u;
  __syncthreads();
  for (int idx = tid; idx < 4 * 160; idx += 256){
    const int b = idx / 160, q = idx - b * 160;
    ((u32*)hbuf)[b * 164 + q] = hstate32[(size_t)(bblk * 4 + b) * 160 + q];
  }

  const u16* xpp = xp + (size_t)bg * 320 + (tW * 16 + lq * 4);
  float*     hhp = hh + (size_t)bg * 320 + (tW * 16 + lq * 4);

  u32x2 xA[5], xB[5];
#pragma unroll
  for (int i = 0; i < 5; ++i) xA[i] = *(const u32x2*)(xpp + i * 16);
#pragma unroll
  for (int i = 0; i < 5; ++i) xB[i] = *(const u32x2*)(xpp + XPS + i * 16);
  const u16* xpre = xpp + 2 * (size_t)XPS;

  __syncthreads();

#define STEP(XV, CURB, NXTB, PREP) do {                                       \
    f32x4 acc[5];                                                             \
    _Pragma("unroll")                                                         \
    for (int i = 0; i < 5; ++i){                                              \
      union { u32x2 u; __fp16 h[4]; } xu; xu.u = XV[i];                       \
      acc[i][0] = (float)xu.h[0]; acc[i][1] = (float)xu.h[1];                 \
      acc[i][2] = (float)xu.h[2]; acc[i][3] = (float)xu.h[3];                 \
    }                                                                         \
    _Pragma("unroll")                                                         \
    for (int i = 0; i < 5; ++i) XV[i] = *(const u32x2*)((PREP) + i * 16);     \
    _Pragma("unroll")                                                         \
    for (int ks = 0; ks < 10; ++ks){                                          \
      const f16x8 bfrag = *(const f16x8*)&hbuf[(CURB) + lm * HROW + ks * 32 + lq * 8]; \
      _Pragma("unroll")                                                       \
      for (int i = 0; i < 5; ++i)                                             \
        acc[i] = __builtin_amdgcn_mfma_f32_16x16x32_f16(aq[i][ks], bfrag, acc[i], 0, 0, 0); \
    }                                                                         \
    _Pragma("unroll")                                                         \
    for (int i = 0; i < 5; ++i){                                              \
      f32x4 hv;                                                               \
      hv[0] = fmaxf(acc[i][0], 0.f); hv[1] = fmaxf(acc[i][1], 0.f);           \
      hv[2] = fmaxf(acc[i][2], 0.f); hv[3] = fmaxf(acc[i][3], 0.f);           \
      if (act) *(f32x4*)(hhp + i * 16) = hv;                                  \
      *(u32x2*)&hbuf[(NXTB) + lm * HROW + ((tW + i) * 16 + lq * 4)] =         \
          (u32x2){pkh2(hv[0], hv[1]), pkh2(hv[2], hv[3])};                    \
    }                                                                         \
    hhp += HHS;                                                               \
    BAR_LDS();                                                                \
  } while (0)

  for (int t = 0; t < len; t += 2){
    const u16* pA = (t + 2 < len) ? xpre         : xpp;   // tail: dummy (unused)
    const u16* pB = (t + 3 < len) ? (xpre + XPS) : xpp;
    STEP(xA, 0, BUF, pA);
    STEP(xB, BUF, 0, pB);
    xpre += 2 * (size_t)XPS;
  }
#undef STEP

  // ---- writeback carry (len even -> final h in buf0), rows 0..3
  for (int idx = tid; idx < 4 * 160; idx += 256){
    const int b = idx / 160, q = idx - b * 160;
    hstate32[(size_t)(bblk * 4 + b) * 160 + q] = ((u32*)hbuf)[b * 164 + q];
  }
}

// ---------------------------------------------------------------------------
// maxout: one block per timestep. Max over 64 batches of hh[s][b][n] (f32),
// then the 2-wide output projection; also emits hT rows at s == S_LEN-1.
// (unchanged from the verified R4/R7 kernel)
// ---------------------------------------------------------------------------
__global__ __launch_bounds__(320) void maxout(
    const float* __restrict__ hh, const void* __restrict__ Wout_raw,
    const void* __restrict__ bout_raw, const int* __restrict__ flag,
    float* __restrict__ dout, int s0)
{
  const int srel = blockIdx.x, s = s0 + srel;
  const int n = threadIdx.x;               // 0..319
  __shared__ float mv[320];

  const float* hp = hh + (size_t)srel * HHS + n;
  const bool wrT = (s == S_LEN - 1) && (n < H_DIM);
  float m = 0.f;
  for (int b = 0; b < 64; ++b){
    const float v = hp[b * 320];
    m = fmaxf(m, v);
    if (wrT) dout[S_LEN * 2 + (size_t)b * H_DIM + n] = v;
  }
  mv[n] = m;
  __syncthreads();

  if (threadIdx.x < 64){
    const bool isf32 = (*flag != 0);
    const int lidx = threadIdx.x;
    float a0 = 0.f, a1 = 0.f;
#pragma unroll
    for (int j = 0; j < 5; ++j){
      const int nn = lidx * 5 + j;
      if (nn < H_DIM){
        float w0, w1;
        if (isf32){ w0 = ((const float*)Wout_raw)[nn]; w1 = ((const float*)Wout_raw)[H_DIM + nn]; }
        else      { w0 = bf2f(((const u16*)Wout_raw)[nn]); w1 = bf2f(((const u16*)Wout_raw)[H_DIM + nn]); }
        a0 = fmaf(mv[nn], w0, a0);
        a1 = fmaf(mv[nn], w1, a1);
      }
    }
    for (int off = 32; off; off >>= 1){
      a0 += __shfl_down(a0, off);
      a1 += __shfl_down(a1, off);
    }
    if (lidx == 0){
      float b0, b1;
      if (isf32){ b0 = ((const float*)bout_raw)[0]; b1 = ((const float*)bout_raw)[1]; }
      else      { b0 = bf2f(((const u16*)bout_raw)[0]); b1 = bf2f(((const u16*)bout_raw)[1]); }
      dout[s * 2 + 0] = a0 + b0;
      dout[s * 2 + 1] = a1 + b1;
    }
  }
}

// ---------------------------------------------------------------------------
extern "C" void kernel_launch(void* const* d_in, const int* in_sizes, int n_in,
                              void* d_out, int out_size, void* d_ws, size_t ws_size,
                              hipStream_t stream)
{
  const int* x  = (const int*)d_in[0];
  const void* emb  = d_in[1];
  const void* Wih  = d_in[2];
  const void* Whh  = d_in[3];
  const void* bih  = d_in[4];
  const void* bhh  = d_in[5];
  const void* Wout = d_in[6];
  const void* bout = d_in[7];
  float* out = (float*)d_out;

  char* ws = (char*)d_ws;
  u16*   Wpad     = (u16*)(ws + OFF_WPAD);
  float* biasp    = (float*)(ws + OFF_BIAS);
  int*   flag     = (int*)(ws + OFF_FLAG);
  u32*   hstate32 = (u32*)(ws + OFF_H);
  u16*   Whhp     = (u16*)(ws + OFF_WHH);
  u16*   xpu      = (u16*)(ws + OFF_XP);

  // chunk size: xp (CH*40,960 B) + hh (CH*81,920 B) must fit
  int CH = 128;
  const int cands[5] = {2048, 1024, 512, 256, 128};
  for (int i = 0; i < 5; ++i){
    if ((size_t)OFF_XP + (size_t)cands[i] * (40960u + 81920u) <= ws_size){ CH = cands[i]; break; }
  }
  const int nchunks = S_LEN / CH;
  float* hh = (float*)(ws + OFF_XP + (size_t)CH * 40960u);

  detect<<<1, 256, 0, stream>>>((const u16*)emb, flag);
  prep<<<400, 256, 0, stream>>>(Wih, Whh, bih, bhh, flag, Wpad, Whhp,
                                biasp, hstate32);
  for (int k = 0; k < nchunks; ++k){
    const int s0 = k * CH;
    xp_gemm<<<CH, 256, 0, stream>>>(x, emb, flag, Wpad, biasp, xpu, s0);
    recur<<<16, 256, 0, stream>>>(xpu, Whhp, hstate32, hh, CH);
    maxout<<<CH, 320, 0, stream>>>(hh, Wout, bout, flag, out, s0);
  }
}